// Round 9
// baseline (330.922 us; speedup 1.0000x reference)
//
#include <hip/hip_runtime.h>

// CombinedLoss: 0.7*MSE + 0.3*mean_b softDTW_gamma.  B=64, T=1024, C=8, fp32.
// R16 = R15 + register-pressure & publisher-path cuts (layout/sync proven,
// kept bit-identical):
//  (1) in-place Dc: DFAST(i) for window u+1 overwrites Dc_i right after
//      RSTEP(i) consumes it -> E array + 16-mov rotation deleted (-20 regs).
//  (2) quarter-wise bottom-row stores: 4 live rh regs instead of 16.
//      VGPR 88 -> ~64: in-order wave can keep more D-loads in flight
//      (suspected hidden stall: mid-window lgkm batch waits).
//  (3) publisher (w_=3,q<3): lane 63 holds the bottom row in registers ->
//      stores the 16 u64 events directly (fire-and-forget), no LDS
//      round-trip (+~250cy was in the rate-setting slot). s_row -> [3][].
//  (4) dm = D+m computed off-chain; rn = fmaf(-c2,lg,dm): -1 add per chain step.
// Geometry/sync unchanged: 256 blocks x 256 thr, 1 wave/SIMD, free-running
// waves, LDS progress flags intra-block, self-validating 8B atomics
// cross-block, 48B-stride padded column layout (bank floor).
// ws: [0,256) mse | [256,320) sdtw | u64 rings @ float-offset 320 (~1.6 MB).

constexpr int TT = 1024;
constexpr float ALPHA_ = 0.7f;
constexpr float FINF = 1000000000.0f;
constexpr int RING = 1088;

__device__ __forceinline__ float shflup1(float old0, float v) {
    return __int_as_float(__builtin_amdgcn_update_dpp(
        __float_as_int(old0), __float_as_int(v), 0x138, 0xf, 0xf, false));
}
__device__ __forceinline__ float rotdn1(float v) {
    return __int_as_float(__builtin_amdgcn_update_dpp(
        0, __float_as_int(v), 0x130, 0xf, 0xf, false));
}

__global__ __launch_bounds__(256) void sdtw_band_kernel(
    const float* __restrict__ pred, const float* __restrict__ target,
    float* __restrict__ ws)
{
    // col j: A-half at 3j, B-half at 3j+1, y2 at 3j+2.x (48B stride)
    __shared__ float4 s_c4[TT * 3];
    __shared__ float  s_row[3][1088];    // waves 0..2 bottom rows (full length)
    __shared__ float  s_red[4];
    __shared__ int    s_prog[4];         // last completed abs window per wave

    const int blk = blockIdx.x;
    const int b   = blk & 63;                  // batch (q*64+b: same-XCD bands)
    const int q   = blk >> 6;                  // band
    const int tid = threadIdx.x;
    const int l   = tid & 63;
    const int w_  = __builtin_amdgcn_readfirstlane(tid >> 6);
    const int g   = (q << 2) + w_;             // global wave 0..15
    const int gbase = g << 6;
    const int row   = gbase + l;

    if (tid < 4) s_prog[tid] = -1;

    const float* pr = pred   + ((size_t)b * TT + row) * 8;
    const float* tr = target + ((size_t)b * TT + row) * 8;
    const float4 pa = ((const float4*)pr)[0];
    const float4 pb = ((const float4*)pr)[1];
    const float4 ma = ((const float4*)tr)[0];
    const float4 mb = ((const float4*)tr)[1];

    float x2 = 0.f, msep = 0.f;
    {
        const float pp[8] = {pa.x,pa.y,pa.z,pa.w,pb.x,pb.y,pb.z,pb.w};
        const float tt[8] = {ma.x,ma.y,ma.z,ma.w,mb.x,mb.y,mb.z,mb.w};
        #pragma unroll
        for (int c = 0; c < 8; ++c) {
            x2 = fmaf(pp[c], pp[c], x2);
            float d = pp[c] - tt[c];
            msep = fmaf(d, d, msep);
        }
    }
    // stage all 1024 columns (4 per thread), padded layout
    const float* tg = target + (size_t)b * TT * 8;
    #pragma unroll
    for (int c0 = 0; c0 < 4; ++c0) {
        const int col = tid + (c0 << 8);
        const float4 u0 = ((const float4*)(tg + (size_t)col * 8))[0];
        const float4 u1 = ((const float4*)(tg + (size_t)col * 8))[1];
        const float y2 = u0.x*u0.x + u0.y*u0.y + u0.z*u0.z + u0.w*u0.w
                       + u1.x*u1.x + u1.y*u1.y + u1.z*u1.z + u1.w*u1.w;
        s_c4[3*col]   = make_float4(-2.f*u0.x, -2.f*u0.y, -2.f*u0.z, -2.f*u0.w);
        s_c4[3*col+1] = make_float4(-2.f*u1.x, -2.f*u1.y, -2.f*u1.z, -2.f*u1.w);
        s_c4[3*col+2] = make_float4(y2, 0.f, 0.f, 0.f);
    }
    #pragma unroll
    for (int off = 32; off > 0; off >>= 1) msep += __shfl_down(msep, off, 64);
    if (l == 0) s_red[w_] = msep;
    __syncthreads();                      // the ONLY block-wide barrier
    if (tid == 0) ws[blk] = s_red[0] + s_red[1] + s_red[2] + s_red[3];

    unsigned long long* rings = (unsigned long long*)(ws + 320);
    unsigned long long* pub = rings + (size_t)(q * 64 + b) * RING;       // w_==3,q<3
    unsigned long long* con = rings + (size_t)((q - 1) * 64 + b) * RING; // w_==0,q>0
    const int kb_pub   = 256 * q + 192;
    const int kb_con   = 256 * q - 64;
    const int kmax_con = kb_con + 1086;

    const float c1 = 7.213475204444817f;     // log2(e)/gamma
    const float c2 = 0.13862943611198906f;   // gamma*ln(2)
    const int amin = g << 2;                 // first abs window = 4g
    const int amax = amin + 67;
    const int prodmax = amin + 63;           // producer wave's amax = 4(g-1)+67

    float r1 = FINF, r2 = FINF;
    unsigned long long pe1 = 0, pe2 = 0;
    int ppf = 0;
    float hpf1 = 0.f, hpf2 = 0.f;
    int hpff = 0;
    float hv, hvd;

    // stage halo hv (diag k0-1) / hvd (diag k0-2), row gbase-1
    auto stage_halo = [&](int a, int k0, int u) {
        if (w_ == 0) {
            if (q == 0) {
                hv  = FINF;
                hvd = (u == 0 && l == 0) ? 0.0f : FINF;
            } else {
                const int kk1 = k0 - 1 + l, kk2 = k0 - 2 + l;
                const int id1 = min(kk1 - kb_con, RING - 1);
                const int id2 = min(kk2 - kb_con, RING - 1);
                const bool n1 = (l < 16) && (kk1 <= kmax_con);
                const bool n2 = (l < 16) && (kk2 <= kmax_con);
                unsigned long long e1, e2;
                if (ppf) { e1 = pe1; e2 = pe2; ppf = 0; }
                else {
                    e1 = __hip_atomic_load(con + id1, __ATOMIC_RELAXED,
                                           __HIP_MEMORY_SCOPE_AGENT);
                    e2 = __hip_atomic_load(con + id2, __ATOMIC_RELAXED,
                                           __HIP_MEMORY_SCOPE_AGENT);
                }
                while (!__all(((!n1) | ((int)(e1 >> 32) == kk1)) &
                              ((!n2) | ((int)(e2 >> 32) == kk2)))) {
                    e1 = __hip_atomic_load(con + id1, __ATOMIC_RELAXED,
                                           __HIP_MEMORY_SCOPE_AGENT);
                    e2 = __hip_atomic_load(con + id2, __ATOMIC_RELAXED,
                                           __HIP_MEMORY_SCOPE_AGENT);
                }
                hv  = n1 ? __uint_as_float((unsigned)e1) : FINF;
                hvd = n2 ? __uint_as_float((unsigned)e2) : FINF;
            }
        } else {
            if (hpff) { hv = hpf1; hvd = hpf2; hpff = 0; }
            else {
                const int need = (a < prodmax) ? a : prodmax;
                int pv;
                do {
                    pv = __hip_atomic_load(&s_prog[w_ - 1], __ATOMIC_ACQUIRE,
                                           __HIP_MEMORY_SCOPE_WORKGROUP);
                } while (pv < need);
                const int bi = (u << 4) + 63 + l;     // k0-1+l in producer row
                hv  = s_row[w_ - 1][min(bi,     1087)];
                hvd = s_row[w_ - 1][min(bi - 1, 1087)];
            }
        }
    };

// ---- D: distance for one diag of window u+1, written IN PLACE into DC ----
#define DFAST(i, DC) do {                                                   \
        const int j_  = jb1 + (i);                                          \
        const float4 va_ = s_c4[3*j_];                                      \
        const float4 vb_ = s_c4[3*j_+1];                                    \
        const float  yv_ = s_c4[3*j_+2].x;                                  \
        float ac_ = x2 + yv_, ac2_ = 0.f;                                   \
        ac_  = fmaf(pa.x, va_.x, ac_ );  ac2_ = fmaf(pa.y, va_.y, ac2_);    \
        ac_  = fmaf(pa.z, va_.z, ac_ );  ac2_ = fmaf(pa.w, va_.w, ac2_);    \
        ac_  = fmaf(pb.x, vb_.x, ac_ );  ac2_ = fmaf(pb.y, vb_.y, ac2_);    \
        ac_  = fmaf(pb.z, vb_.z, ac_ );  ac2_ = fmaf(pb.w, vb_.w, ac2_);    \
        DC = ac_ + ac2_;                                                    \
    } while (0)

// clamped path (edge windows)
#define DCLAMP(JB, i, DC) do {                                              \
        int jc_ = (JB) + (i);                                               \
        jc_ = jc_ < 0 ? 0 : (jc_ > (TT-1) ? (TT-1) : jc_);                  \
        const float4 va_ = s_c4[3*jc_];                                     \
        const float4 vb_ = s_c4[3*jc_+1];                                   \
        const float  yv_ = s_c4[3*jc_+2].x;                                 \
        float ac_ = x2 + yv_, ac2_ = 0.f;                                   \
        ac_  = fmaf(pa.x, va_.x, ac_ );  ac2_ = fmaf(pa.y, va_.y, ac2_);    \
        ac_  = fmaf(pa.z, va_.z, ac_ );  ac2_ = fmaf(pa.w, va_.w, ac2_);    \
        ac_  = fmaf(pb.x, vb_.x, ac_ );  ac2_ = fmaf(pb.y, vb_.y, ac2_);    \
        ac_  = fmaf(pb.z, vb_.z, ac_ );  ac2_ = fmaf(pb.w, vb_.w, ac2_);    \
        DC = ac_ + ac2_;                                                    \
    } while (0)

// ---- R: one softmin recurrence step.  dm = D+m computed OFF the chain. ----
#define RSTEP(i, DIN, RH, MASKED) do {                                      \
        const float up_   = shflup1(hv,  r1);                               \
        const float dgv_  = shflup1(hvd, r2);                               \
        const float left_ = r1;                                             \
        hv = rotdn1(hv); hvd = rotdn1(hvd);                                 \
        float m_, M_;                                                       \
        asm("v_min3_f32 %0, %1, %2, %3"                                     \
            : "=v"(m_) : "v"(up_), "v"(left_), "v"(dgv_));                  \
        asm("v_max3_f32 %0, %1, %2, %3"                                     \
            : "=v"(M_) : "v"(up_), "v"(left_), "v"(dgv_));                  \
        const float md_ = __builtin_amdgcn_fmed3f(up_, left_, dgv_);        \
        const float dm_ = (DIN) + m_;                                       \
        const float mc_ = m_ * c1;                                          \
        const float ea_ = __builtin_amdgcn_exp2f(fmaf(md_, -c1, mc_));      \
        const float eb_ = __builtin_amdgcn_exp2f(fmaf(M_,  -c1, mc_));      \
        const float lg_ = __builtin_amdgcn_logf(1.0f + (ea_ + eb_));        \
        float rn_ = fmaf(-c2, lg_, dm_);                                    \
        if (MASKED)                                                         \
            rn_ = ((unsigned)(jb0 + (i)) < (unsigned)TT) ? rn_ : FINF;      \
        r2 = r1; r1 = rn_; RH = rn_;                                        \
    } while (0)

// ---- quarter bottom-row store / register-direct publish ----
#define STQ(QI, Ra, Rb, Rc, Rd) do {                                        \
        if (w_ < 3) {                                                       \
            if (l == 63)                                                    \
                *(float4*)&s_row[w_][(u << 4) + (QI)*4] =                   \
                    make_float4(Ra, Rb, Rc, Rd);                            \
        } else if (q < 3) {                                                 \
            if (l == 63) {                                                  \
                const int kq_ = k0 + (QI)*4;                                \
                __hip_atomic_store(pub + (kq_     - kb_pub),                \
                    ((unsigned long long)(unsigned)(kq_    ) << 32) |       \
                    (unsigned long long)__float_as_uint(Ra),                \
                    __ATOMIC_RELAXED, __HIP_MEMORY_SCOPE_AGENT);            \
                __hip_atomic_store(pub + (kq_ + 1 - kb_pub),                \
                    ((unsigned long long)(unsigned)(kq_ + 1) << 32) |       \
                    (unsigned long long)__float_as_uint(Rb),                \
                    __ATOMIC_RELAXED, __HIP_MEMORY_SCOPE_AGENT);            \
                __hip_atomic_store(pub + (kq_ + 2 - kb_pub),                \
                    ((unsigned long long)(unsigned)(kq_ + 2) << 32) |       \
                    (unsigned long long)__float_as_uint(Rc),                \
                    __ATOMIC_RELAXED, __HIP_MEMORY_SCOPE_AGENT);            \
                __hip_atomic_store(pub + (kq_ + 3 - kb_pub),                \
                    ((unsigned long long)(unsigned)(kq_ + 3) << 32) |       \
                    (unsigned long long)__float_as_uint(Rd),                \
                    __ATOMIC_RELAXED, __HIP_MEMORY_SCOPE_AGENT);            \
            }                                                               \
        }                                                                   \
    } while (0)

    // D for window 0 (prologue, clamped)
    float Dc0,Dc1,Dc2,Dc3,Dc4,Dc5,Dc6,Dc7;
    float Dc8,Dc9,Dc10,Dc11,Dc12,Dc13,Dc14,Dc15;
    {
        const int jb = -l;
        DCLAMP(jb, 0,Dc0 ); DCLAMP(jb, 1,Dc1 ); DCLAMP(jb, 2,Dc2 );
        DCLAMP(jb, 3,Dc3 ); DCLAMP(jb, 4,Dc4 ); DCLAMP(jb, 5,Dc5 );
        DCLAMP(jb, 6,Dc6 ); DCLAMP(jb, 7,Dc7 ); DCLAMP(jb, 8,Dc8 );
        DCLAMP(jb, 9,Dc9 ); DCLAMP(jb,10,Dc10); DCLAMP(jb,11,Dc11);
        DCLAMP(jb,12,Dc12); DCLAMP(jb,13,Dc13); DCLAMP(jb,14,Dc14);
        DCLAMP(jb,15,Dc15);
    }
    float rh14_last = FINF;

    for (int u = 0; u <= 67; ++u) {
        const int a  = amin + u;
        const int k0 = a << 4;
        const int jb0 = (u << 4) - l;        // col index of diag k0 at this lane
        const int jb1 = jb0 + 16;            // same for window u+1

        stage_halo(a, k0, u);

        float t0, t1, t2, t3;

        if (u >= 4 && u <= 62) {
            // hot fused path: R(u) with D(u+1) written in place, quarter stores
            RSTEP( 0,Dc0 ,t0,0); DFAST( 0,Dc0 );
            RSTEP( 1,Dc1 ,t1,0); DFAST( 1,Dc1 );
            RSTEP( 2,Dc2 ,t2,0); DFAST( 2,Dc2 );
            RSTEP( 3,Dc3 ,t3,0); DFAST( 3,Dc3 );
            STQ(0, t0, t1, t2, t3);
            RSTEP( 4,Dc4 ,t0,0); DFAST( 4,Dc4 );
            RSTEP( 5,Dc5 ,t1,0); DFAST( 5,Dc5 );
            RSTEP( 6,Dc6 ,t2,0); DFAST( 6,Dc6 );
            RSTEP( 7,Dc7 ,t3,0); DFAST( 7,Dc7 );
            STQ(1, t0, t1, t2, t3);
            RSTEP( 8,Dc8 ,t0,0); DFAST( 8,Dc8 );
            RSTEP( 9,Dc9 ,t1,0); DFAST( 9,Dc9 );
            RSTEP(10,Dc10,t2,0); DFAST(10,Dc10);
            RSTEP(11,Dc11,t3,0); DFAST(11,Dc11);
            STQ(2, t0, t1, t2, t3);
            RSTEP(12,Dc12,t0,0); DFAST(12,Dc12);
            RSTEP(13,Dc13,t1,0); DFAST(13,Dc13);
            RSTEP(14,Dc14,t2,0); DFAST(14,Dc14);
            RSTEP(15,Dc15,t3,0); DFAST(15,Dc15);
            STQ(3, t0, t1, t2, t3);
        } else {
            // edge windows: masked R; clamped D for u+1 (skip at u=67)
            RSTEP( 0,Dc0 ,t0,1);
            if (u < 67) DCLAMP(jb1, 0,Dc0 );
            RSTEP( 1,Dc1 ,t1,1);
            if (u < 67) DCLAMP(jb1, 1,Dc1 );
            RSTEP( 2,Dc2 ,t2,1);
            if (u < 67) DCLAMP(jb1, 2,Dc2 );
            RSTEP( 3,Dc3 ,t3,1);
            if (u < 67) DCLAMP(jb1, 3,Dc3 );
            STQ(0, t0, t1, t2, t3);
            RSTEP( 4,Dc4 ,t0,1);
            if (u < 67) DCLAMP(jb1, 4,Dc4 );
            RSTEP( 5,Dc5 ,t1,1);
            if (u < 67) DCLAMP(jb1, 5,Dc5 );
            RSTEP( 6,Dc6 ,t2,1);
            if (u < 67) DCLAMP(jb1, 6,Dc6 );
            RSTEP( 7,Dc7 ,t3,1);
            if (u < 67) DCLAMP(jb1, 7,Dc7 );
            STQ(1, t0, t1, t2, t3);
            RSTEP( 8,Dc8 ,t0,1);
            if (u < 67) DCLAMP(jb1, 8,Dc8 );
            RSTEP( 9,Dc9 ,t1,1);
            if (u < 67) DCLAMP(jb1, 9,Dc9 );
            RSTEP(10,Dc10,t2,1);
            if (u < 67) DCLAMP(jb1,10,Dc10);
            RSTEP(11,Dc11,t3,1);
            if (u < 67) DCLAMP(jb1,11,Dc11);
            STQ(2, t0, t1, t2, t3);
            RSTEP(12,Dc12,t0,1);
            if (u < 67) DCLAMP(jb1,12,Dc12);
            RSTEP(13,Dc13,t1,1);
            if (u < 67) DCLAMP(jb1,13,Dc13);
            RSTEP(14,Dc14,t2,1);
            if (u < 67) DCLAMP(jb1,14,Dc14);
            RSTEP(15,Dc15,t3,1);
            if (u < 67) DCLAMP(jb1,15,Dc15);
            STQ(3, t0, t1, t2, t3);
            if (u == 67) rh14_last = t2;     // r_{2T-2}(T-1) at diag 2046
        }

        // ---- mark window complete for intra-block consumer ----
        if (w_ < 3 && l == 0) {
            __hip_atomic_store(&s_prog[w_], a, __ATOMIC_RELEASE,
                               __HIP_MEMORY_SCOPE_WORKGROUP);
        }
        // ---- cross-block consumer: prefetch next window's halo entries ----
        if (w_ == 0 && q > 0 && a < amax) {
            const int k0n = k0 + 16;
            const int kk1 = k0n - 1 + l, kk2 = k0n - 2 + l;
            pe1 = __hip_atomic_load(con + min(kk1 - kb_con, RING - 1),
                                    __ATOMIC_RELAXED, __HIP_MEMORY_SCOPE_AGENT);
            pe2 = __hip_atomic_load(con + min(kk2 - kb_con, RING - 1),
                                    __ATOMIC_RELAXED, __HIP_MEMORY_SCOPE_AGENT);
            ppf = 1;
        }
        // ---- intra-block consumer: prefetch next window's halo if ready ----
        if (w_ != 0 && a < amax) {
            const int neednx = ((a + 1) < prodmax) ? (a + 1) : prodmax;
            const int pv = __hip_atomic_load(&s_prog[w_ - 1], __ATOMIC_ACQUIRE,
                                             __HIP_MEMORY_SCOPE_WORKGROUP);
            if (pv >= neednx) {
                const int bi = ((u + 1) << 4) + 63 + l;
                hpf1 = s_row[w_ - 1][min(bi,     1087)];
                hpf2 = s_row[w_ - 1][min(bi - 1, 1087)];
                hpff = 1;
            }
        }
    }
    if (q == 3 && tid == 255) ws[256 + b] = rh14_last;   // r_{2T-2}(T-1)
#undef DFAST
#undef DCLAMP
#undef RSTEP
#undef STQ
}

__global__ __launch_bounds__(256) void finalize2_kernel(
    const float* __restrict__ ws, float* __restrict__ out)
{
    __shared__ float sm[4], ss[4];
    const int tid = threadIdx.x, l = tid & 63, w = tid >> 6;
    float m  = ws[tid];
    float sd = (tid < 64) ? ws[256 + tid] : 0.f;
    #pragma unroll
    for (int off = 32; off > 0; off >>= 1) {
        m  += __shfl_down(m,  off, 64);
        sd += __shfl_down(sd, off, 64);
    }
    if (l == 0) { sm[w] = m; ss[w] = sd; }
    __syncthreads();
    if (tid == 0) {
        float M = sm[0] + sm[1] + sm[2] + sm[3];
        float S = ss[0] + ss[1] + ss[2] + ss[3];
        out[0] = ALPHA_ * (M / 524288.0f) + (1.0f - ALPHA_) * (S / 64.0f);
    }
}

extern "C" void kernel_launch(void* const* d_in, const int* in_sizes, int n_in,
                              void* d_out, int out_size, void* d_ws, size_t ws_size,
                              hipStream_t stream) {
    const float* pred   = (const float*)d_in[0];
    const float* target = (const float*)d_in[1];
    float* ws  = (float*)d_ws;
    float* out = (float*)d_out;

    sdtw_band_kernel<<<256, 256, 0, stream>>>(pred, target, ws);
    finalize2_kernel<<<1, 256, 0, stream>>>(ws, out);
}

// Round 11
// 311.426 us; speedup vs baseline: 1.0626x; 1.0626x over previous
//
#include <hip/hip_runtime.h>

// CombinedLoss: 0.7*MSE + 0.3*mean_b softDTW_gamma.  B=64, T=1024, C=8, fp32.
// R18 (= R17 resubmit; round-10 bench died at container acquire again --
// same infra signature as round 5, which passed on verbatim resubmit.
// Audit: sync/OOB/rotation all clean).
// R17 = R15 + 2-step-deep D-load pipeline.  Diagnosis: ds_read latency
// ~120cy (m117) was never pipelined -- DFAST consumed its own loads ~25cy
// after issue, exposing ~100cy x 16 steps ~= the ~3k cy/window unattributed
// stall (issue 1.1k + chain 1k overlap fine).  Fix: DLOADP(i) issues 3
// ds_reads into rotating buf[i%3]; DMATHP consumes buf[(i-2)%3] two full
// steps (~110cy of RSTEP+DLOAD work) later.  +27 VGPR, free at 1 block/CU.
// RSTEP/publisher/sync/layout bit-identical to R15: 48B-stride padded
// columns (bank floor), 256 blocks x 256 thr, 1 wave/SIMD, free-running
// waves, LDS progress flags intra-block, self-validating 8B atomics
// cross-block.
// ws: [0,256) mse | [256,320) sdtw | u64 rings @ float-offset 320 (~1.6 MB).

constexpr int TT = 1024;
constexpr float ALPHA_ = 0.7f;
constexpr float FINF = 1000000000.0f;
constexpr int RING = 1088;

__device__ __forceinline__ float shflup1(float old0, float v) {
    return __int_as_float(__builtin_amdgcn_update_dpp(
        __float_as_int(old0), __float_as_int(v), 0x138, 0xf, 0xf, false));
}
__device__ __forceinline__ float rotdn1(float v) {
    return __int_as_float(__builtin_amdgcn_update_dpp(
        0, __float_as_int(v), 0x130, 0xf, 0xf, false));
}

__global__ __launch_bounds__(256) void sdtw_band_kernel(
    const float* __restrict__ pred, const float* __restrict__ target,
    float* __restrict__ ws)
{
    // col j: A-half at 3j, B-half at 3j+1, y2 at 3j+2.x (48B stride)
    __shared__ float4 s_c4[TT * 3];
    __shared__ float  s_row[4][1088];    // per-wave bottom row, full length
    __shared__ float  s_red[4];
    __shared__ int    s_prog[4];         // last completed abs window per wave

    const int blk = blockIdx.x;
    const int b   = blk & 63;                  // batch (q*64+b: same-XCD bands)
    const int q   = blk >> 6;                  // band
    const int tid = threadIdx.x;
    const int l   = tid & 63;
    const int w_  = __builtin_amdgcn_readfirstlane(tid >> 6);
    const int g   = (q << 2) + w_;             // global wave 0..15
    const int gbase = g << 6;
    const int row   = gbase + l;

    if (tid < 4) s_prog[tid] = -1;

    const float* pr = pred   + ((size_t)b * TT + row) * 8;
    const float* tr = target + ((size_t)b * TT + row) * 8;
    const float4 pa = ((const float4*)pr)[0];
    const float4 pb = ((const float4*)pr)[1];
    const float4 ma = ((const float4*)tr)[0];
    const float4 mb = ((const float4*)tr)[1];

    float x2 = 0.f, msep = 0.f;
    {
        const float pp[8] = {pa.x,pa.y,pa.z,pa.w,pb.x,pb.y,pb.z,pb.w};
        const float tt[8] = {ma.x,ma.y,ma.z,ma.w,mb.x,mb.y,mb.z,mb.w};
        #pragma unroll
        for (int c = 0; c < 8; ++c) {
            x2 = fmaf(pp[c], pp[c], x2);
            float d = pp[c] - tt[c];
            msep = fmaf(d, d, msep);
        }
    }
    // stage all 1024 columns (4 per thread), padded layout
    const float* tg = target + (size_t)b * TT * 8;
    #pragma unroll
    for (int c0 = 0; c0 < 4; ++c0) {
        const int col = tid + (c0 << 8);
        const float4 u0 = ((const float4*)(tg + (size_t)col * 8))[0];
        const float4 u1 = ((const float4*)(tg + (size_t)col * 8))[1];
        const float y2 = u0.x*u0.x + u0.y*u0.y + u0.z*u0.z + u0.w*u0.w
                       + u1.x*u1.x + u1.y*u1.y + u1.z*u1.z + u1.w*u1.w;
        s_c4[3*col]   = make_float4(-2.f*u0.x, -2.f*u0.y, -2.f*u0.z, -2.f*u0.w);
        s_c4[3*col+1] = make_float4(-2.f*u1.x, -2.f*u1.y, -2.f*u1.z, -2.f*u1.w);
        s_c4[3*col+2] = make_float4(y2, 0.f, 0.f, 0.f);
    }
    #pragma unroll
    for (int off = 32; off > 0; off >>= 1) msep += __shfl_down(msep, off, 64);
    if (l == 0) s_red[w_] = msep;
    __syncthreads();                      // the ONLY block-wide barrier
    if (tid == 0) ws[blk] = s_red[0] + s_red[1] + s_red[2] + s_red[3];

    unsigned long long* rings = (unsigned long long*)(ws + 320);
    unsigned long long* pub = rings + (size_t)(q * 64 + b) * RING;       // w_==3,q<3
    unsigned long long* con = rings + (size_t)((q - 1) * 64 + b) * RING; // w_==0,q>0
    const int kb_pub   = 256 * q + 192;
    const int kb_con   = 256 * q - 64;
    const int kmax_con = kb_con + 1086;

    const float c1 = 7.213475204444817f;     // log2(e)/gamma
    const float c2 = 0.13862943611198906f;   // gamma*ln(2)
    const int amin = g << 2;                 // first abs window = 4g
    const int amax = amin + 67;
    const int prodmax = amin + 63;           // producer wave's amax = 4(g-1)+67

    float r1 = FINF, r2 = FINF;
    unsigned long long pe1 = 0, pe2 = 0;
    int ppf = 0;
    float hpf1 = 0.f, hpf2 = 0.f;
    int hpff = 0;
    float hv, hvd;

    // stage halo hv (diag k0-1) / hvd (diag k0-2), row gbase-1
    auto stage_halo = [&](int a, int k0, int u) {
        if (w_ == 0) {
            if (q == 0) {
                hv  = FINF;
                hvd = (u == 0 && l == 0) ? 0.0f : FINF;
            } else {
                const int kk1 = k0 - 1 + l, kk2 = k0 - 2 + l;
                const int id1 = min(kk1 - kb_con, RING - 1);
                const int id2 = min(kk2 - kb_con, RING - 1);
                const bool n1 = (l < 16) && (kk1 <= kmax_con);
                const bool n2 = (l < 16) && (kk2 <= kmax_con);
                unsigned long long e1, e2;
                if (ppf) { e1 = pe1; e2 = pe2; ppf = 0; }
                else {
                    e1 = __hip_atomic_load(con + id1, __ATOMIC_RELAXED,
                                           __HIP_MEMORY_SCOPE_AGENT);
                    e2 = __hip_atomic_load(con + id2, __ATOMIC_RELAXED,
                                           __HIP_MEMORY_SCOPE_AGENT);
                }
                while (!__all(((!n1) | ((int)(e1 >> 32) == kk1)) &
                              ((!n2) | ((int)(e2 >> 32) == kk2)))) {
                    e1 = __hip_atomic_load(con + id1, __ATOMIC_RELAXED,
                                           __HIP_MEMORY_SCOPE_AGENT);
                    e2 = __hip_atomic_load(con + id2, __ATOMIC_RELAXED,
                                           __HIP_MEMORY_SCOPE_AGENT);
                }
                hv  = n1 ? __uint_as_float((unsigned)e1) : FINF;
                hvd = n2 ? __uint_as_float((unsigned)e2) : FINF;
            }
        } else {
            if (hpff) { hv = hpf1; hvd = hpf2; hpff = 0; }
            else {
                const int need = (a < prodmax) ? a : prodmax;
                int pv;
                do {
                    pv = __hip_atomic_load(&s_prog[w_ - 1], __ATOMIC_ACQUIRE,
                                           __HIP_MEMORY_SCOPE_WORKGROUP);
                } while (pv < need);
                const int bi = (u << 4) + 63 + l;     // k0-1+l in producer row
                hv  = s_row[w_ - 1][min(bi,     1087)];
                hvd = s_row[w_ - 1][min(bi - 1, 1087)];
            }
        }
    };

// ---- pipelined D: load raw column into a named buffer (3 ds_reads) ----
#define DLOADP(i, VA, VB, YV) do {                                          \
        const int j_  = jb1 + (i);                                          \
        VA = s_c4[3*j_];                                                    \
        VB = s_c4[3*j_+1];                                                  \
        YV = s_c4[3*j_+2].x;                                                \
    } while (0)

// ---- pipelined D: consume a buffer loaded 2 steps ago ----
#define DMATHP(VA, VB, YV, DST) do {                                        \
        float ac_ = x2 + YV, ac2_ = 0.f;                                    \
        ac_  = fmaf(pa.x, VA.x, ac_ );  ac2_ = fmaf(pa.y, VA.y, ac2_);      \
        ac_  = fmaf(pa.z, VA.z, ac_ );  ac2_ = fmaf(pa.w, VA.w, ac2_);      \
        ac_  = fmaf(pb.x, VB.x, ac_ );  ac2_ = fmaf(pb.y, VB.y, ac2_);      \
        ac_  = fmaf(pb.z, VB.z, ac_ );  ac2_ = fmaf(pb.w, VB.w, ac2_);      \
        DST = ac_ + ac2_;                                                   \
    } while (0)

// clamped path (edge windows, immediate consume)
#define DCLAMP(JB, i, DST) do {                                             \
        int jc_ = (JB) + (i);                                               \
        jc_ = jc_ < 0 ? 0 : (jc_ > (TT-1) ? (TT-1) : jc_);                  \
        const float4 va_ = s_c4[3*jc_];                                     \
        const float4 vb_ = s_c4[3*jc_+1];                                   \
        const float  yv_ = s_c4[3*jc_+2].x;                                 \
        float ac_ = x2 + yv_, ac2_ = 0.f;                                   \
        ac_  = fmaf(pa.x, va_.x, ac_ );  ac2_ = fmaf(pa.y, va_.y, ac2_);    \
        ac_  = fmaf(pa.z, va_.z, ac_ );  ac2_ = fmaf(pa.w, va_.w, ac2_);    \
        ac_  = fmaf(pb.x, vb_.x, ac_ );  ac2_ = fmaf(pb.y, vb_.y, ac2_);    \
        ac_  = fmaf(pb.z, vb_.z, ac_ );  ac2_ = fmaf(pb.w, vb_.w, ac2_);    \
        DST = ac_ + ac2_;                                                   \
    } while (0)

// ---- R: one softmin recurrence step (bit-identical to R15). ----
#define RSTEP(i, DIN, RH, MASKED) do {                                      \
        const float up_   = shflup1(hv,  r1);                               \
        const float dgv_  = shflup1(hvd, r2);                               \
        const float left_ = r1;                                             \
        hv = rotdn1(hv); hvd = rotdn1(hvd);                                 \
        float m_, M_;                                                       \
        asm("v_min3_f32 %0, %1, %2, %3"                                     \
            : "=v"(m_) : "v"(up_), "v"(left_), "v"(dgv_));                  \
        asm("v_max3_f32 %0, %1, %2, %3"                                     \
            : "=v"(M_) : "v"(up_), "v"(left_), "v"(dgv_));                  \
        const float md_ = __builtin_amdgcn_fmed3f(up_, left_, dgv_);        \
        const float mc_ = m_ * c1;                                          \
        const float ea_ = __builtin_amdgcn_exp2f(fmaf(md_, -c1, mc_));      \
        const float eb_ = __builtin_amdgcn_exp2f(fmaf(M_,  -c1, mc_));      \
        const float lg_ = __builtin_amdgcn_logf(1.0f + (ea_ + eb_));        \
        float rn_ = (DIN) + fmaf(-c2, lg_, m_);                             \
        if (MASKED)                                                         \
            rn_ = ((unsigned)(jb0 + (i)) < (unsigned)TT) ? rn_ : FINF;      \
        r2 = r1; r1 = rn_; RH = rn_;                                        \
    } while (0)

    // D for window 0 (prologue, clamped)
    float Dc0,Dc1,Dc2,Dc3,Dc4,Dc5,Dc6,Dc7;
    float Dc8,Dc9,Dc10,Dc11,Dc12,Dc13,Dc14,Dc15;
    {
        const int jb = -l;
        DCLAMP(jb, 0,Dc0 ); DCLAMP(jb, 1,Dc1 ); DCLAMP(jb, 2,Dc2 );
        DCLAMP(jb, 3,Dc3 ); DCLAMP(jb, 4,Dc4 ); DCLAMP(jb, 5,Dc5 );
        DCLAMP(jb, 6,Dc6 ); DCLAMP(jb, 7,Dc7 ); DCLAMP(jb, 8,Dc8 );
        DCLAMP(jb, 9,Dc9 ); DCLAMP(jb,10,Dc10); DCLAMP(jb,11,Dc11);
        DCLAMP(jb,12,Dc12); DCLAMP(jb,13,Dc13); DCLAMP(jb,14,Dc14);
        DCLAMP(jb,15,Dc15);
    }
    float rh14_last = FINF;
    // rotating load buffers (2-step-deep pipeline)
    float4 vA0, vB0, vA1, vB1, vA2, vB2;
    float  yv0, yv1, yv2;

    for (int u = 0; u <= 67; ++u) {
        const int a  = amin + u;
        const int k0 = a << 4;
        const int jb0 = (u << 4) - l;        // col index of diag k0 at this lane
        const int jb1 = jb0 + 16;            // same for window u+1

        stage_halo(a, k0, u);

        float E0,E1,E2,E3,E4,E5,E6,E7,E8,E9,E10,E11,E12,E13,E14,E15;
        float rh0,rh1,rh2,rh3,rh4,rh5,rh6,rh7;
        float rh8,rh9,rh10,rh11,rh12,rh13,rh14,rh15;

        if (u >= 4 && u <= 62) {
            // hot fused path: R(u) + 2-step-pipelined D(u+1)
            RSTEP( 0,Dc0 ,rh0 ,0); DLOADP( 0,vA0,vB0,yv0);
            RSTEP( 1,Dc1 ,rh1 ,0); DLOADP( 1,vA1,vB1,yv1);
            RSTEP( 2,Dc2 ,rh2 ,0); DLOADP( 2,vA2,vB2,yv2); DMATHP(vA0,vB0,yv0,E0 );
            RSTEP( 3,Dc3 ,rh3 ,0); DLOADP( 3,vA0,vB0,yv0); DMATHP(vA1,vB1,yv1,E1 );
            RSTEP( 4,Dc4 ,rh4 ,0); DLOADP( 4,vA1,vB1,yv1); DMATHP(vA2,vB2,yv2,E2 );
            RSTEP( 5,Dc5 ,rh5 ,0); DLOADP( 5,vA2,vB2,yv2); DMATHP(vA0,vB0,yv0,E3 );
            RSTEP( 6,Dc6 ,rh6 ,0); DLOADP( 6,vA0,vB0,yv0); DMATHP(vA1,vB1,yv1,E4 );
            RSTEP( 7,Dc7 ,rh7 ,0); DLOADP( 7,vA1,vB1,yv1); DMATHP(vA2,vB2,yv2,E5 );
            RSTEP( 8,Dc8 ,rh8 ,0); DLOADP( 8,vA2,vB2,yv2); DMATHP(vA0,vB0,yv0,E6 );
            RSTEP( 9,Dc9 ,rh9 ,0); DLOADP( 9,vA0,vB0,yv0); DMATHP(vA1,vB1,yv1,E7 );
            RSTEP(10,Dc10,rh10,0); DLOADP(10,vA1,vB1,yv1); DMATHP(vA2,vB2,yv2,E8 );
            RSTEP(11,Dc11,rh11,0); DLOADP(11,vA2,vB2,yv2); DMATHP(vA0,vB0,yv0,E9 );
            RSTEP(12,Dc12,rh12,0); DLOADP(12,vA0,vB0,yv0); DMATHP(vA1,vB1,yv1,E10);
            RSTEP(13,Dc13,rh13,0); DLOADP(13,vA1,vB1,yv1); DMATHP(vA2,vB2,yv2,E11);
            RSTEP(14,Dc14,rh14,0); DLOADP(14,vA2,vB2,yv2); DMATHP(vA0,vB0,yv0,E12);
            RSTEP(15,Dc15,rh15,0); DLOADP(15,vA0,vB0,yv0); DMATHP(vA1,vB1,yv1,E13);
            DMATHP(vA2,vB2,yv2,E14);
            DMATHP(vA0,vB0,yv0,E15);
        } else {
            // edge windows: masked R; clamped D for u+1 (skip at u=67)
            RSTEP( 0,Dc0 ,rh0 ,1); RSTEP( 1,Dc1 ,rh1 ,1);
            RSTEP( 2,Dc2 ,rh2 ,1); RSTEP( 3,Dc3 ,rh3 ,1);
            RSTEP( 4,Dc4 ,rh4 ,1); RSTEP( 5,Dc5 ,rh5 ,1);
            RSTEP( 6,Dc6 ,rh6 ,1); RSTEP( 7,Dc7 ,rh7 ,1);
            RSTEP( 8,Dc8 ,rh8 ,1); RSTEP( 9,Dc9 ,rh9 ,1);
            RSTEP(10,Dc10,rh10,1); RSTEP(11,Dc11,rh11,1);
            RSTEP(12,Dc12,rh12,1); RSTEP(13,Dc13,rh13,1);
            RSTEP(14,Dc14,rh14,1); RSTEP(15,Dc15,rh15,1);
            if (u < 67) {
                DCLAMP(jb1, 0,E0 ); DCLAMP(jb1, 1,E1 ); DCLAMP(jb1, 2,E2 );
                DCLAMP(jb1, 3,E3 ); DCLAMP(jb1, 4,E4 ); DCLAMP(jb1, 5,E5 );
                DCLAMP(jb1, 6,E6 ); DCLAMP(jb1, 7,E7 ); DCLAMP(jb1, 8,E8 );
                DCLAMP(jb1, 9,E9 ); DCLAMP(jb1,10,E10); DCLAMP(jb1,11,E11);
                DCLAMP(jb1,12,E12); DCLAMP(jb1,13,E13); DCLAMP(jb1,14,E14);
                DCLAMP(jb1,15,E15);
            } else {
                E0=E1=E2=E3=E4=E5=E6=E7=0.f;
                E8=E9=E10=E11=E12=E13=E14=E15=0.f;
                rh14_last = rh14;
            }
        }

        // bottom-row store (packed; masked FINF entries are correct values)
        if (l == 63) {
            float4* dst = (float4*)&s_row[w_][u << 4];
            dst[0] = make_float4(rh0,  rh1,  rh2,  rh3);
            dst[1] = make_float4(rh4,  rh5,  rh6,  rh7);
            dst[2] = make_float4(rh8,  rh9,  rh10, rh11);
            dst[3] = make_float4(rh12, rh13, rh14, rh15);
        }
        // rotate D buffers
        Dc0=E0;  Dc1=E1;  Dc2=E2;  Dc3=E3;  Dc4=E4;  Dc5=E5;  Dc6=E6;  Dc7=E7;
        Dc8=E8;  Dc9=E9;  Dc10=E10;Dc11=E11;Dc12=E12;Dc13=E13;Dc14=E14;Dc15=E15;

        // ---- mark window complete for intra-block consumer ----
        if (w_ < 3 && l == 0) {
            __hip_atomic_store(&s_prog[w_], a, __ATOMIC_RELEASE,
                               __HIP_MEMORY_SCOPE_WORKGROUP);
        }
        // ---- producer: publish window as self-validating u64 entries ----
        if (w_ == 3 && q < 3) {
            if (l < 16) {
                const int kk = k0 + l;
                const unsigned long long ev =
                    ((unsigned long long)(unsigned)kk << 32) |
                    (unsigned long long)__float_as_uint(s_row[3][(u << 4) + l]);
                __hip_atomic_store(pub + (kk - kb_pub), ev,
                                   __ATOMIC_RELAXED, __HIP_MEMORY_SCOPE_AGENT);
            }
        }
        // ---- cross-block consumer: prefetch next window's halo entries ----
        if (w_ == 0 && q > 0 && a < amax) {
            const int k0n = k0 + 16;
            const int kk1 = k0n - 1 + l, kk2 = k0n - 2 + l;
            pe1 = __hip_atomic_load(con + min(kk1 - kb_con, RING - 1),
                                    __ATOMIC_RELAXED, __HIP_MEMORY_SCOPE_AGENT);
            pe2 = __hip_atomic_load(con + min(kk2 - kb_con, RING - 1),
                                    __ATOMIC_RELAXED, __HIP_MEMORY_SCOPE_AGENT);
            ppf = 1;
        }
        // ---- intra-block consumer: prefetch next window's halo if ready ----
        if (w_ != 0 && a < amax) {
            const int neednx = ((a + 1) < prodmax) ? (a + 1) : prodmax;
            const int pv = __hip_atomic_load(&s_prog[w_ - 1], __ATOMIC_ACQUIRE,
                                             __HIP_MEMORY_SCOPE_WORKGROUP);
            if (pv >= neednx) {
                const int bi = ((u + 1) << 4) + 63 + l;
                hpf1 = s_row[w_ - 1][min(bi,     1087)];
                hpf2 = s_row[w_ - 1][min(bi - 1, 1087)];
                hpff = 1;
            }
        }
    }
    if (q == 3 && tid == 255) ws[256 + b] = rh14_last;   // r_{2T-2}(T-1)
#undef DLOADP
#undef DMATHP
#undef DCLAMP
#undef RSTEP
}

__global__ __launch_bounds__(256) void finalize2_kernel(
    const float* __restrict__ ws, float* __restrict__ out)
{
    __shared__ float sm[4], ss[4];
    const int tid = threadIdx.x, l = tid & 63, w = tid >> 6;
    float m  = ws[tid];
    float sd = (tid < 64) ? ws[256 + tid] : 0.f;
    #pragma unroll
    for (int off = 32; off > 0; off >>= 1) {
        m  += __shfl_down(m,  off, 64);
        sd += __shfl_down(sd, off, 64);
    }
    if (l == 0) { sm[w] = m; ss[w] = sd; }
    __syncthreads();
    if (tid == 0) {
        float M = sm[0] + sm[1] + sm[2] + sm[3];
        float S = ss[0] + ss[1] + ss[2] + ss[3];
        out[0] = ALPHA_ * (M / 524288.0f) + (1.0f - ALPHA_) * (S / 64.0f);
    }
}

extern "C" void kernel_launch(void* const* d_in, const int* in_sizes, int n_in,
                              void* d_out, int out_size, void* d_ws, size_t ws_size,
                              hipStream_t stream) {
    const float* pred   = (const float*)d_in[0];
    const float* target = (const float*)d_in[1];
    float* ws  = (float*)d_ws;
    float* out = (float*)d_out;

    sdtw_band_kernel<<<256, 256, 0, stream>>>(pred, target, ws);
    finalize2_kernel<<<1, 256, 0, stream>>>(ws, out);
}

// Round 12
// 307.174 us; speedup vs baseline: 1.0773x; 1.0138x over previous
//
#include <hip/hip_runtime.h>

// CombinedLoss: 0.7*MSE + 0.3*mean_b softDTW_gamma.  B=64, T=1024, C=8, fp32.
// R19: overlap the softmin chain with D-work INSIDE each step + dg=up_prev.
// R18 proved issue(135cy/diag) and chain(140cy/diag) are fully serialized:
// in-order issue stalls at every chain link since chain ops are adjacent in
// program order.  Fixes: (1) dg(d) == up(d-1) EXACTLY (shflup1(hvd,r2) ==
// shflup1(hv@(d-1), r1@(d-1))) -> carry up_prev in a register; hvd halo path
// (staging/spin/prefetch/2 DPP+2 mov per step) deleted; hvd staged once
// pre-loop to seed dgp.  (2) each step's 3 ds_reads issued inside the chain
// head; step i-2's 10-FMA D-math placed between the exp2s and the log.
// (3) in-place Dc (E array + rotation deleted).
// Geometry/sync otherwise R15: 48B-stride padded columns, 256 blocks x 256
// thr, 1 wave/SIMD, free-running waves, LDS progress flags intra-block,
// self-validating 8B atomics cross-block.
// ws: [0,256) mse | [256,320) sdtw | u64 rings @ float-offset 320 (~1.6 MB).

constexpr int TT = 1024;
constexpr float ALPHA_ = 0.7f;
constexpr float FINF = 1000000000.0f;
constexpr int RING = 1088;

__device__ __forceinline__ float shflup1(float old0, float v) {
    return __int_as_float(__builtin_amdgcn_update_dpp(
        __float_as_int(old0), __float_as_int(v), 0x138, 0xf, 0xf, false));
}
__device__ __forceinline__ float rotdn1(float v) {
    return __int_as_float(__builtin_amdgcn_update_dpp(
        0, __float_as_int(v), 0x130, 0xf, 0xf, false));
}

__global__ __launch_bounds__(256) void sdtw_band_kernel(
    const float* __restrict__ pred, const float* __restrict__ target,
    float* __restrict__ ws)
{
    // col j: A-half at 3j, B-half at 3j+1, y2 at 3j+2.x (48B stride)
    __shared__ float4 s_c4[TT * 3];
    __shared__ float  s_row[4][1088];    // per-wave bottom row, full length
    __shared__ float  s_red[4];
    __shared__ int    s_prog[4];         // last completed abs window per wave

    const int blk = blockIdx.x;
    const int b   = blk & 63;                  // batch (q*64+b: same-XCD bands)
    const int q   = blk >> 6;                  // band
    const int tid = threadIdx.x;
    const int l   = tid & 63;
    const int w_  = __builtin_amdgcn_readfirstlane(tid >> 6);
    const int g   = (q << 2) + w_;             // global wave 0..15
    const int gbase = g << 6;
    const int row   = gbase + l;

    if (tid < 4) s_prog[tid] = -1;

    const float* pr = pred   + ((size_t)b * TT + row) * 8;
    const float* tr = target + ((size_t)b * TT + row) * 8;
    const float4 pa = ((const float4*)pr)[0];
    const float4 pb = ((const float4*)pr)[1];
    const float4 ma = ((const float4*)tr)[0];
    const float4 mb = ((const float4*)tr)[1];

    float x2 = 0.f, msep = 0.f;
    {
        const float pp[8] = {pa.x,pa.y,pa.z,pa.w,pb.x,pb.y,pb.z,pb.w};
        const float tt[8] = {ma.x,ma.y,ma.z,ma.w,mb.x,mb.y,mb.z,mb.w};
        #pragma unroll
        for (int c = 0; c < 8; ++c) {
            x2 = fmaf(pp[c], pp[c], x2);
            float d = pp[c] - tt[c];
            msep = fmaf(d, d, msep);
        }
    }
    // stage all 1024 columns (4 per thread), padded layout
    const float* tg = target + (size_t)b * TT * 8;
    #pragma unroll
    for (int c0 = 0; c0 < 4; ++c0) {
        const int col = tid + (c0 << 8);
        const float4 u0 = ((const float4*)(tg + (size_t)col * 8))[0];
        const float4 u1 = ((const float4*)(tg + (size_t)col * 8))[1];
        const float y2 = u0.x*u0.x + u0.y*u0.y + u0.z*u0.z + u0.w*u0.w
                       + u1.x*u1.x + u1.y*u1.y + u1.z*u1.z + u1.w*u1.w;
        s_c4[3*col]   = make_float4(-2.f*u0.x, -2.f*u0.y, -2.f*u0.z, -2.f*u0.w);
        s_c4[3*col+1] = make_float4(-2.f*u1.x, -2.f*u1.y, -2.f*u1.z, -2.f*u1.w);
        s_c4[3*col+2] = make_float4(y2, 0.f, 0.f, 0.f);
    }
    #pragma unroll
    for (int off = 32; off > 0; off >>= 1) msep += __shfl_down(msep, off, 64);
    if (l == 0) s_red[w_] = msep;
    __syncthreads();                      // the ONLY block-wide barrier
    if (tid == 0) ws[blk] = s_red[0] + s_red[1] + s_red[2] + s_red[3];

    unsigned long long* rings = (unsigned long long*)(ws + 320);
    unsigned long long* pub = rings + (size_t)(q * 64 + b) * RING;       // w_==3,q<3
    unsigned long long* con = rings + (size_t)((q - 1) * 64 + b) * RING; // w_==0,q>0
    const int kb_pub   = 256 * q + 192;
    const int kb_con   = 256 * q - 64;
    const int kmax_con = kb_con + 1086;

    const float c1 = 7.213475204444817f;     // log2(e)/gamma
    const float c2 = 0.13862943611198906f;   // gamma*ln(2)
    const int amin = g << 2;                 // first abs window = 4g
    const int amax = amin + 67;
    const int prodmax = amin + 63;           // producer wave's amax = 4(g-1)+67

    float r1 = FINF;
    float dgp;                               // dg(d) = up(d-1), carried
    unsigned long long pe1 = 0;
    int ppf = 0;
    float hpf1 = 0.f;
    int hpff = 0;
    float hv;

    // ---- pre-loop: stage hvd for the FIRST window only, seed dgp ----
    {
        float hvd0;
        if (w_ == 0) {
            if (q == 0) {
                hvd0 = (l == 0) ? 0.0f : FINF;
            } else {
                const int kk2 = (amin << 4) - 2 + l;
                const int id2 = min(kk2 - kb_con, RING - 1);
                const bool n2 = (l < 16) && (kk2 <= kmax_con);
                unsigned long long e2;
                do {
                    e2 = __hip_atomic_load(con + id2, __ATOMIC_RELAXED,
                                           __HIP_MEMORY_SCOPE_AGENT);
                } while (!__all((!n2) | ((int)(e2 >> 32) == kk2)));
                hvd0 = n2 ? __uint_as_float((unsigned)e2) : FINF;
            }
        } else {
            const int need0 = (amin < prodmax) ? amin : prodmax;
            int pv;
            do {
                pv = __hip_atomic_load(&s_prog[w_ - 1], __ATOMIC_ACQUIRE,
                                       __HIP_MEMORY_SCOPE_WORKGROUP);
            } while (pv < need0);
            hvd0 = s_row[w_ - 1][min(62 + l, 1087)];
        }
        dgp = shflup1(hvd0, FINF);           // lane0 <- hvd0[0], others FINF
    }

// ---- hot step: chain with in-chain D load (step i) + D math (step i-2) ----
#define STEPF(i, BA,BB,BY, CA,CB,CY, DCI, DC2, RH) do {                     \
        const float up_ = shflup1(hv, r1);                                  \
        hv = rotdn1(hv);                                                    \
        const int j_ = jb1 + (i);                                           \
        BA = s_c4[3*j_]; BB = s_c4[3*j_+1]; BY = s_c4[3*j_+2].x;            \
        float m_, M_;                                                       \
        asm("v_min3_f32 %0, %1, %2, %3"                                     \
            : "=v"(m_) : "v"(up_), "v"(r1), "v"(dgp));                      \
        asm("v_max3_f32 %0, %1, %2, %3"                                     \
            : "=v"(M_) : "v"(up_), "v"(r1), "v"(dgp));                      \
        const float md_ = __builtin_amdgcn_fmed3f(up_, r1, dgp);            \
        dgp = up_;                                                          \
        const float mc_ = m_ * c1;                                          \
        const float ea_ = __builtin_amdgcn_exp2f(fmaf(md_, -c1, mc_));      \
        const float eb_ = __builtin_amdgcn_exp2f(fmaf(M_,  -c1, mc_));      \
        {   float ac_ = x2 + CY, ac2_ = 0.f;                                \
            ac_  = fmaf(pa.x, CA.x, ac_ );  ac2_ = fmaf(pa.y, CA.y, ac2_);  \
            ac_  = fmaf(pa.z, CA.z, ac_ );  ac2_ = fmaf(pa.w, CA.w, ac2_);  \
            ac_  = fmaf(pb.x, CB.x, ac_ );  ac2_ = fmaf(pb.y, CB.y, ac2_);  \
            ac_  = fmaf(pb.z, CB.z, ac_ );  ac2_ = fmaf(pb.w, CB.w, ac2_);  \
            DC2 = ac_ + ac2_; }                                             \
        const float lg_ = __builtin_amdgcn_logf(1.0f + (ea_ + eb_));        \
        const float rn_ = (DCI) + fmaf(-c2, lg_, m_);                       \
        r1 = rn_; RH = rn_;                                                 \
    } while (0)

// hot step without the i-2 math (steps 0,1; their consumers ran in prev tail)
#define STEPF0(i, BA,BB,BY, DCI, RH) do {                                   \
        const float up_ = shflup1(hv, r1);                                  \
        hv = rotdn1(hv);                                                    \
        const int j_ = jb1 + (i);                                           \
        BA = s_c4[3*j_]; BB = s_c4[3*j_+1]; BY = s_c4[3*j_+2].x;            \
        float m_, M_;                                                       \
        asm("v_min3_f32 %0, %1, %2, %3"                                     \
            : "=v"(m_) : "v"(up_), "v"(r1), "v"(dgp));                      \
        asm("v_max3_f32 %0, %1, %2, %3"                                     \
            : "=v"(M_) : "v"(up_), "v"(r1), "v"(dgp));                      \
        const float md_ = __builtin_amdgcn_fmed3f(up_, r1, dgp);            \
        dgp = up_;                                                          \
        const float mc_ = m_ * c1;                                          \
        const float ea_ = __builtin_amdgcn_exp2f(fmaf(md_, -c1, mc_));      \
        const float eb_ = __builtin_amdgcn_exp2f(fmaf(M_,  -c1, mc_));      \
        const float lg_ = __builtin_amdgcn_logf(1.0f + (ea_ + eb_));        \
        const float rn_ = (DCI) + fmaf(-c2, lg_, m_);                       \
        r1 = rn_; RH = rn_;                                                 \
    } while (0)

// tail math for the last two loads of a hot window
#define DMATHT(CA,CB,CY, DC2) do {                                          \
        float ac_ = x2 + CY, ac2_ = 0.f;                                    \
        ac_  = fmaf(pa.x, CA.x, ac_ );  ac2_ = fmaf(pa.y, CA.y, ac2_);      \
        ac_  = fmaf(pa.z, CA.z, ac_ );  ac2_ = fmaf(pa.w, CA.w, ac2_);      \
        ac_  = fmaf(pb.x, CB.x, ac_ );  ac2_ = fmaf(pb.y, CB.y, ac2_);      \
        ac_  = fmaf(pb.z, CB.z, ac_ );  ac2_ = fmaf(pb.w, CB.w, ac2_);      \
        DC2 = ac_ + ac2_;                                                   \
    } while (0)

// edge step: masked recurrence, no load pipeline
#define STEPE(i, DCI, RH) do {                                              \
        const float up_ = shflup1(hv, r1);                                  \
        hv = rotdn1(hv);                                                    \
        float m_, M_;                                                       \
        asm("v_min3_f32 %0, %1, %2, %3"                                     \
            : "=v"(m_) : "v"(up_), "v"(r1), "v"(dgp));                      \
        asm("v_max3_f32 %0, %1, %2, %3"                                     \
            : "=v"(M_) : "v"(up_), "v"(r1), "v"(dgp));                      \
        const float md_ = __builtin_amdgcn_fmed3f(up_, r1, dgp);            \
        dgp = up_;                                                          \
        const float mc_ = m_ * c1;                                          \
        const float ea_ = __builtin_amdgcn_exp2f(fmaf(md_, -c1, mc_));      \
        const float eb_ = __builtin_amdgcn_exp2f(fmaf(M_,  -c1, mc_));      \
        const float lg_ = __builtin_amdgcn_logf(1.0f + (ea_ + eb_));        \
        float rn_ = (DCI) + fmaf(-c2, lg_, m_);                             \
        rn_ = ((unsigned)(jb0 + (i)) < (unsigned)TT) ? rn_ : FINF;          \
        r1 = rn_; RH = rn_;                                                 \
    } while (0)

// clamped D (edge windows / prologue)
#define DCLAMP(JB, i, DC) do {                                              \
        int jc_ = (JB) + (i);                                               \
        jc_ = jc_ < 0 ? 0 : (jc_ > (TT-1) ? (TT-1) : jc_);                  \
        const float4 va_ = s_c4[3*jc_];                                     \
        const float4 vb_ = s_c4[3*jc_+1];                                   \
        const float  yv_ = s_c4[3*jc_+2].x;                                 \
        float ac_ = x2 + yv_, ac2_ = 0.f;                                   \
        ac_  = fmaf(pa.x, va_.x, ac_ );  ac2_ = fmaf(pa.y, va_.y, ac2_);    \
        ac_  = fmaf(pa.z, va_.z, ac_ );  ac2_ = fmaf(pa.w, va_.w, ac2_);    \
        ac_  = fmaf(pb.x, vb_.x, ac_ );  ac2_ = fmaf(pb.y, vb_.y, ac2_);    \
        ac_  = fmaf(pb.z, vb_.z, ac_ );  ac2_ = fmaf(pb.w, vb_.w, ac2_);    \
        DC = ac_ + ac2_;                                                    \
    } while (0)

    // D for window 0 (prologue, clamped)
    float Dc0,Dc1,Dc2,Dc3,Dc4,Dc5,Dc6,Dc7;
    float Dc8,Dc9,Dc10,Dc11,Dc12,Dc13,Dc14,Dc15;
    {
        const int jb = -l;
        DCLAMP(jb, 0,Dc0 ); DCLAMP(jb, 1,Dc1 ); DCLAMP(jb, 2,Dc2 );
        DCLAMP(jb, 3,Dc3 ); DCLAMP(jb, 4,Dc4 ); DCLAMP(jb, 5,Dc5 );
        DCLAMP(jb, 6,Dc6 ); DCLAMP(jb, 7,Dc7 ); DCLAMP(jb, 8,Dc8 );
        DCLAMP(jb, 9,Dc9 ); DCLAMP(jb,10,Dc10); DCLAMP(jb,11,Dc11);
        DCLAMP(jb,12,Dc12); DCLAMP(jb,13,Dc13); DCLAMP(jb,14,Dc14);
        DCLAMP(jb,15,Dc15);
    }
    float rh14_last = FINF;
    float4 vA0, vB0, vA1, vB1, vA2, vB2;
    float  yv0, yv1, yv2;

    for (int u = 0; u <= 67; ++u) {
        const int a  = amin + u;
        const int k0 = a << 4;
        const int jb0 = (u << 4) - l;        // col index of diag k0 at this lane
        const int jb1 = jb0 + 16;            // same for window u+1

        // ---- stage halo hv (diag k0-1) only ----
        if (w_ == 0) {
            if (q == 0) {
                hv = FINF;
            } else {
                const int kk1 = k0 - 1 + l;
                const int id1 = min(kk1 - kb_con, RING - 1);
                const bool n1 = (l < 16) && (kk1 <= kmax_con);
                unsigned long long e1;
                if (ppf) { e1 = pe1; ppf = 0; }
                else {
                    e1 = __hip_atomic_load(con + id1, __ATOMIC_RELAXED,
                                           __HIP_MEMORY_SCOPE_AGENT);
                }
                while (!__all((!n1) | ((int)(e1 >> 32) == kk1))) {
                    e1 = __hip_atomic_load(con + id1, __ATOMIC_RELAXED,
                                           __HIP_MEMORY_SCOPE_AGENT);
                }
                hv = n1 ? __uint_as_float((unsigned)e1) : FINF;
            }
        } else {
            if (hpff) { hv = hpf1; hpff = 0; }
            else {
                const int need = (a < prodmax) ? a : prodmax;
                int pv;
                do {
                    pv = __hip_atomic_load(&s_prog[w_ - 1], __ATOMIC_ACQUIRE,
                                           __HIP_MEMORY_SCOPE_WORKGROUP);
                } while (pv < need);
                hv = s_row[w_ - 1][min((u << 4) + 63 + l, 1087)];
            }
        }

        float rh0,rh1,rh2,rh3,rh4,rh5,rh6,rh7;
        float rh8,rh9,rh10,rh11,rh12,rh13,rh14,rh15;

        if (u >= 4 && u <= 62) {
            STEPF0( 0, vA0,vB0,yv0,               Dc0 , rh0 );
            STEPF0( 1, vA1,vB1,yv1,               Dc1 , rh1 );
            STEPF ( 2, vA2,vB2,yv2, vA0,vB0,yv0,  Dc2 , Dc0 , rh2 );
            STEPF ( 3, vA0,vB0,yv0, vA1,vB1,yv1,  Dc3 , Dc1 , rh3 );
            STEPF ( 4, vA1,vB1,yv1, vA2,vB2,yv2,  Dc4 , Dc2 , rh4 );
            STEPF ( 5, vA2,vB2,yv2, vA0,vB0,yv0,  Dc5 , Dc3 , rh5 );
            STEPF ( 6, vA0,vB0,yv0, vA1,vB1,yv1,  Dc6 , Dc4 , rh6 );
            STEPF ( 7, vA1,vB1,yv1, vA2,vB2,yv2,  Dc7 , Dc5 , rh7 );
            STEPF ( 8, vA2,vB2,yv2, vA0,vB0,yv0,  Dc8 , Dc6 , rh8 );
            STEPF ( 9, vA0,vB0,yv0, vA1,vB1,yv1,  Dc9 , Dc7 , rh9 );
            STEPF (10, vA1,vB1,yv1, vA2,vB2,yv2,  Dc10, Dc8 , rh10);
            STEPF (11, vA2,vB2,yv2, vA0,vB0,yv0,  Dc11, Dc9 , rh11);
            STEPF (12, vA0,vB0,yv0, vA1,vB1,yv1,  Dc12, Dc10, rh12);
            STEPF (13, vA1,vB1,yv1, vA2,vB2,yv2,  Dc13, Dc11, rh13);
            STEPF (14, vA2,vB2,yv2, vA0,vB0,yv0,  Dc14, Dc12, rh14);
            STEPF (15, vA0,vB0,yv0, vA1,vB1,yv1,  Dc15, Dc13, rh15);
            DMATHT(vA2,vB2,yv2, Dc14);
            DMATHT(vA0,vB0,yv0, Dc15);
        } else {
            STEPE( 0,Dc0 ,rh0 ); STEPE( 1,Dc1 ,rh1 );
            STEPE( 2,Dc2 ,rh2 ); STEPE( 3,Dc3 ,rh3 );
            STEPE( 4,Dc4 ,rh4 ); STEPE( 5,Dc5 ,rh5 );
            STEPE( 6,Dc6 ,rh6 ); STEPE( 7,Dc7 ,rh7 );
            STEPE( 8,Dc8 ,rh8 ); STEPE( 9,Dc9 ,rh9 );
            STEPE(10,Dc10,rh10); STEPE(11,Dc11,rh11);
            STEPE(12,Dc12,rh12); STEPE(13,Dc13,rh13);
            STEPE(14,Dc14,rh14); STEPE(15,Dc15,rh15);
            if (u < 67) {
                DCLAMP(jb1, 0,Dc0 ); DCLAMP(jb1, 1,Dc1 ); DCLAMP(jb1, 2,Dc2 );
                DCLAMP(jb1, 3,Dc3 ); DCLAMP(jb1, 4,Dc4 ); DCLAMP(jb1, 5,Dc5 );
                DCLAMP(jb1, 6,Dc6 ); DCLAMP(jb1, 7,Dc7 ); DCLAMP(jb1, 8,Dc8 );
                DCLAMP(jb1, 9,Dc9 ); DCLAMP(jb1,10,Dc10); DCLAMP(jb1,11,Dc11);
                DCLAMP(jb1,12,Dc12); DCLAMP(jb1,13,Dc13); DCLAMP(jb1,14,Dc14);
                DCLAMP(jb1,15,Dc15);
            } else {
                rh14_last = rh14;
            }
        }

        // bottom-row store (packed; masked FINF entries are correct values)
        if (l == 63) {
            float4* dst = (float4*)&s_row[w_][u << 4];
            dst[0] = make_float4(rh0,  rh1,  rh2,  rh3);
            dst[1] = make_float4(rh4,  rh5,  rh6,  rh7);
            dst[2] = make_float4(rh8,  rh9,  rh10, rh11);
            dst[3] = make_float4(rh12, rh13, rh14, rh15);
        }

        // ---- mark window complete for intra-block consumer ----
        if (w_ < 3 && l == 0) {
            __hip_atomic_store(&s_prog[w_], a, __ATOMIC_RELEASE,
                               __HIP_MEMORY_SCOPE_WORKGROUP);
        }
        // ---- producer: publish window as self-validating u64 entries ----
        if (w_ == 3 && q < 3) {
            if (l < 16) {
                const int kk = k0 + l;
                const unsigned long long ev =
                    ((unsigned long long)(unsigned)kk << 32) |
                    (unsigned long long)__float_as_uint(s_row[3][(u << 4) + l]);
                __hip_atomic_store(pub + (kk - kb_pub), ev,
                                   __ATOMIC_RELAXED, __HIP_MEMORY_SCOPE_AGENT);
            }
        }
        // ---- cross-block consumer: prefetch next window's hv entries ----
        if (w_ == 0 && q > 0 && a < amax) {
            const int kk1 = k0 + 15 + l;
            pe1 = __hip_atomic_load(con + min(kk1 - kb_con, RING - 1),
                                    __ATOMIC_RELAXED, __HIP_MEMORY_SCOPE_AGENT);
            ppf = 1;
        }
        // ---- intra-block consumer: prefetch next window's hv if ready ----
        if (w_ != 0 && a < amax) {
            const int neednx = ((a + 1) < prodmax) ? (a + 1) : prodmax;
            const int pv = __hip_atomic_load(&s_prog[w_ - 1], __ATOMIC_ACQUIRE,
                                             __HIP_MEMORY_SCOPE_WORKGROUP);
            if (pv >= neednx) {
                hpf1 = s_row[w_ - 1][min(((u + 1) << 4) + 63 + l, 1087)];
                hpff = 1;
            }
        }
    }
    if (q == 3 && tid == 255) ws[256 + b] = rh14_last;   // r_{2T-2}(T-1)
#undef STEPF
#undef STEPF0
#undef DMATHT
#undef STEPE
#undef DCLAMP
}

__global__ __launch_bounds__(256) void finalize2_kernel(
    const float* __restrict__ ws, float* __restrict__ out)
{
    __shared__ float sm[4], ss[4];
    const int tid = threadIdx.x, l = tid & 63, w = tid >> 6;
    float m  = ws[tid];
    float sd = (tid < 64) ? ws[256 + tid] : 0.f;
    #pragma unroll
    for (int off = 32; off > 0; off >>= 1) {
        m  += __shfl_down(m,  off, 64);
        sd += __shfl_down(sd, off, 64);
    }
    if (l == 0) { sm[w] = m; ss[w] = sd; }
    __syncthreads();
    if (tid == 0) {
        float M = sm[0] + sm[1] + sm[2] + sm[3];
        float S = ss[0] + ss[1] + ss[2] + ss[3];
        out[0] = ALPHA_ * (M / 524288.0f) + (1.0f - ALPHA_) * (S / 64.0f);
    }
}

extern "C" void kernel_launch(void* const* d_in, const int* in_sizes, int n_in,
                              void* d_out, int out_size, void* d_ws, size_t ws_size,
                              hipStream_t stream) {
    const float* pred   = (const float*)d_in[0];
    const float* target = (const float*)d_in[1];
    float* ws  = (float*)d_ws;
    float* out = (float*)d_out;

    sdtw_band_kernel<<<256, 256, 0, stream>>>(pred, target, ws);
    finalize2_kernel<<<1, 256, 0, stream>>>(ws, out);
}